// Round 10
// baseline (658.948 us; speedup 1.0000x reference)
//
#include <hip/hip_runtime.h>
#include <hip/hip_bf16.h>
#include <math.h>

#define B_ 4
#define L_ 2048
#define D_ 1024
#define E_ 2048
#define N_ 16
#define DD_ 64
#define DCONV_ 4

#define S_SEG 64
#define SEGLEN_ (L_ / S_SEG)   // 32

#define KS_ 4
#define KSUB_ (E_ / KS_)       // 512

typedef __attribute__((ext_vector_type(8))) short bf16x8;
typedef __attribute__((ext_vector_type(4))) float f32x4;

typedef __attribute__((address_space(1))) const void gvoid_t;
typedef __attribute__((address_space(3))) void lvoid_t;

static __device__ __forceinline__ float silu_f(float x) {
    return x / (1.f + __expf(-x));
}

static __device__ __forceinline__ ushort f2bf(float f) {
    __hip_bfloat16 h = __float2bfloat16(f);
    return *reinterpret_cast<ushort*>(&h);
}

static __device__ __forceinline__ float bf2f(ushort u) {
    uint v = ((uint)u) << 16;
    return __uint_as_float(v);
}

#define LOG2E_ 1.4426950408889634f

// ---------------- RMSNorm: resid [B*L, D] -> xn (bf16) ----------------
__global__ __launch_bounds__(256) void k_rmsnorm_bf(const float* __restrict__ resid,
                                                    const float* __restrict__ nw,
                                                    ushort* __restrict__ out) {
    int row = blockIdx.x;
    const float* r = resid + (size_t)row * D_;
    int t = threadIdx.x;
    float4 v = *reinterpret_cast<const float4*>(&r[t * 4]);
    float ss = v.x * v.x + v.y * v.y + v.z * v.z + v.w * v.w;
#pragma unroll
    for (int o = 32; o >= 1; o >>= 1) ss += __shfl_xor(ss, o, 64);
    __shared__ float red[4];
    if ((t & 63) == 0) red[t >> 6] = ss;
    __syncthreads();
    float tot = red[0] + red[1] + red[2] + red[3];
    float rs = rsqrtf(tot * (1.f / (float)D_) + 1e-5f);
    float4 w4 = *reinterpret_cast<const float4*>(&nw[t * 4]);
    ushort4 o4;
    o4.x = f2bf(v.x * rs * w4.x);
    o4.y = f2bf(v.y * rs * w4.y);
    o4.z = f2bf(v.z * rs * w4.z);
    o4.w = f2bf(v.w * rs * w4.w);
    *reinterpret_cast<ushort4*>(&out[(size_t)row * D_ + t * 4]) = o4;
}

// ---------------- single fused f32->bf16 weight cast ----------------
__global__ __launch_bounds__(256) void k_cast_all(const float* __restrict__ skip_w,
                                                  const float* __restrict__ in_w,
                                                  const float* __restrict__ out_w,
                                                  const float* __restrict__ WB,
                                                  const float* __restrict__ WC,
                                                  const float* __restrict__ Wd1,
                                                  const float* __restrict__ Wd2,
                                                  ushort* __restrict__ w2,
                                                  ushort* __restrict__ outw,
                                                  ushort* __restrict__ wbc,
                                                  ushort* __restrict__ wd2) {
    int i = blockIdx.x * 256 + threadIdx.x;
    const float* src;
    ushort* dst;
    int off;
    if (i < 524288)       { src = skip_w; dst = w2;            off = i; }
    else if (i < 1048576) { src = in_w;   dst = w2 + 2097152;  off = i - 524288; }
    else if (i < 1572864) { src = out_w;  dst = outw;          off = i - 1048576; }
    else if (i < 1581056) { src = WB;     dst = wbc;           off = i - 1572864; }
    else if (i < 1589248) { src = WC;     dst = wbc + 32768;   off = i - 1581056; }
    else if (i < 1622016) { src = Wd1;    dst = wbc + 65536;   off = i - 1589248; }
    else                  { src = Wd2;    dst = wd2;           off = i - 1622016; }
    float4 v = *reinterpret_cast<const float4*>(&src[(size_t)off * 4]);
    ushort4 o;
    o.x = f2bf(v.x); o.y = f2bf(v.y); o.z = f2bf(v.z); o.w = f2bf(v.w);
    *reinterpret_cast<ushort4*>(&dst[(size_t)off * 4]) = o;
}

// ---------------- bf16 MFMA GEMM (global_load_lds staging, coalesced LDS epilogue) ----
// C = A[M,K] @ W[N,K]^T
// EPI 1: softplus(acc+bias[n]) -> bf16 Cbf (stride N)
// EPI 2: acc + addsrc -> f32 Cf (stride N)
// EPI 3: split at ncol 2048: bf16 Cbf (skip) / bf16 Cbf2 (xin), both stride 2048
template <int EPI>
__global__ __launch_bounds__(256) void k_gemm_bf(const ushort* __restrict__ A,
                                                 const ushort* __restrict__ W,
                                                 const float* __restrict__ bias,
                                                 const float* __restrict__ addsrc,
                                                 float* __restrict__ Cf,
                                                 ushort* __restrict__ Cbf,
                                                 ushort* __restrict__ Cbf2,
                                                 int M, int N, int K) {
    constexpr int BM = 128, BN = 128, BK = 32;
    constexpr int EPAD = 68;   // 272B row stride: every epilogue phase = 2 lanes/bank (free)
    union SM {
        ushort stage[2 * BM * BK];     // As | Ws  (16 KB)
        float  epi[4][16][EPAD];       // per-wave epilogue scratch (17.4 KB)
    };
    __shared__ __align__(16) SM sm;
    ushort* As = sm.stage;
    ushort* Ws = sm.stage + BM * BK;

    int t = threadIdx.x;
    int m0 = blockIdx.y * BM, n0 = blockIdx.x * BN;
    int wave = t >> 6, lane = t & 63;
    int wr = wave >> 1, wc = wave & 1;
    int lr = lane & 15, lg = lane >> 4;
    int srow = lane >> 2;
    int scol = (lane & 3) * 8;

    f32x4 acc[4][4] = {};

    for (int k0 = 0; k0 < K; k0 += BK) {
#pragma unroll
        for (int p = 0; p < 2; ++p) {
            int seg = wave * 2 + p;
            int row = seg * 16 + srow;
            __builtin_amdgcn_global_load_lds(
                (gvoid_t*)(A + (size_t)(m0 + row) * K + k0 + scol),
                (lvoid_t*)(As + seg * 512), 16, 0, 0);
            __builtin_amdgcn_global_load_lds(
                (gvoid_t*)(W + (size_t)(n0 + row) * K + k0 + scol),
                (lvoid_t*)(Ws + seg * 512), 16, 0, 0);
        }
        __syncthreads();
        bf16x8 af[4], bfr[4];
#pragma unroll
        for (int i = 0; i < 4; ++i) {
            af[i]  = *reinterpret_cast<const bf16x8*>(&As[(wr * 64 + i * 16 + lr) * BK + lg * 8]);
            bfr[i] = *reinterpret_cast<const bf16x8*>(&Ws[(wc * 64 + i * 16 + lr) * BK + lg * 8]);
        }
#pragma unroll
        for (int i = 0; i < 4; ++i)
#pragma unroll
            for (int j = 0; j < 4; ++j)
                acc[i][j] = __builtin_amdgcn_mfma_f32_16x16x32_bf16(af[i], bfr[j], acc[i][j], 0, 0, 0);
        __syncthreads();
    }

    // ---- coalesced epilogue: per-wave 16x64 subtile through LDS ----
    int er = lane >> 2;            // 0..15 row within subtile
    int ec = (lane & 3) * 16;      // col chunk base (16 elems)
#pragma unroll
    for (int i = 0; i < 4; ++i) {
#pragma unroll
        for (int j = 0; j < 4; ++j)
#pragma unroll
            for (int q = 0; q < 4; ++q)
                sm.epi[wave][lg * 4 + q][j * 16 + lr] = acc[i][j][q];
        float vals[16];
#pragma unroll
        for (int v4 = 0; v4 < 4; ++v4) {
            f32x4 tmp = *reinterpret_cast<const f32x4*>(&sm.epi[wave][er][ec + v4 * 4]);
            vals[v4 * 4 + 0] = tmp[0]; vals[v4 * 4 + 1] = tmp[1];
            vals[v4 * 4 + 2] = tmp[2]; vals[v4 * 4 + 3] = tmp[3];
        }
        int grow = m0 + wr * 64 + i * 16 + er;
        int gcol = n0 + wc * 64 + ec;

        if (EPI == 1) {
            ushort u[16];
#pragma unroll
            for (int k = 0; k < 16; ++k) {
                float z = vals[k] + bias[gcol + k];
                u[k] = f2bf((z > 20.f) ? z : log1pf(expf(z)));
            }
            *reinterpret_cast<uint4*>(&Cbf[(size_t)grow * N + gcol]) = *reinterpret_cast<uint4*>(&u[0]);
            *reinterpret_cast<uint4*>(&Cbf[(size_t)grow * N + gcol + 8]) = *reinterpret_cast<uint4*>(&u[8]);
        } else if (EPI == 2) {
#pragma unroll
            for (int v4 = 0; v4 < 4; ++v4) {
                f32x4 r4 = *reinterpret_cast<const f32x4*>(&addsrc[(size_t)grow * N + gcol + v4 * 4]);
                f32x4 o4;
#pragma unroll
                for (int k = 0; k < 4; ++k) o4[k] = vals[v4 * 4 + k] + r4[k];
                *reinterpret_cast<f32x4*>(&Cf[(size_t)grow * N + gcol + v4 * 4]) = o4;
            }
        } else {  // EPI == 3
            ushort u[16];
#pragma unroll
            for (int k = 0; k < 16; ++k) u[k] = f2bf(vals[k]);
            if (gcol < 2048) {
                *reinterpret_cast<uint4*>(&Cbf[(size_t)grow * 2048 + gcol]) = *reinterpret_cast<uint4*>(&u[0]);
                *reinterpret_cast<uint4*>(&Cbf[(size_t)grow * 2048 + gcol + 8]) = *reinterpret_cast<uint4*>(&u[8]);
            } else {
                int c2 = gcol - 2048;
                *reinterpret_cast<uint4*>(&Cbf2[(size_t)grow * 2048 + c2]) = *reinterpret_cast<uint4*>(&u[0]);
                *reinterpret_cast<uint4*>(&Cbf2[(size_t)grow * 2048 + c2 + 8]) = *reinterpret_cast<uint4*>(&u[8]);
            }
        }
    }
}

// ---------------- skinny projections, K-split: part[ks][M][96] = xs_bf @ wbc^T ----------------
__global__ __launch_bounds__(256) void k_proj(const ushort* __restrict__ A,
                                              const ushort* __restrict__ Wc,
                                              float* __restrict__ part) {
    constexpr int BK = 32, LDB = 40;
    __shared__ __align__(16) ushort As[32 * LDB];
    __shared__ __align__(16) ushort Ws[96 * LDB];
    int t = threadIdx.x;
    int m0 = blockIdx.x * 32;
    int ks = blockIdx.y;
    int wave = t >> 6, lane = t & 63;
    int rowbase = (wave >> 1) * 16;
    int colbase = (wave & 1) * 48;
    int lr = lane & 15, lg = lane >> 4;

    f32x4 acc[3] = {};

    for (int k0 = ks * KSUB_; k0 < (ks + 1) * KSUB_; k0 += BK) {
        if (t < 128) {
            int row = t >> 2;
            int cg = (t & 3) * 8;
            *reinterpret_cast<uint4*>(&As[row * LDB + cg]) =
                *reinterpret_cast<const uint4*>(&A[(size_t)(m0 + row) * E_ + k0 + cg]);
        }
        {
            int row = t >> 2, cg = (t & 3) * 8;
            *reinterpret_cast<uint4*>(&Ws[row * LDB + cg]) =
                *reinterpret_cast<const uint4*>(&Wc[(size_t)row * E_ + k0 + cg]);
            if (t < 128) {
                int f2 = t + 256;
                int row2 = f2 >> 2, cg2 = (f2 & 3) * 8;
                *reinterpret_cast<uint4*>(&Ws[row2 * LDB + cg2]) =
                    *reinterpret_cast<const uint4*>(&Wc[(size_t)row2 * E_ + k0 + cg2]);
            }
        }
        __syncthreads();
        bf16x8 af = *reinterpret_cast<const bf16x8*>(&As[(rowbase + lr) * LDB + lg * 8]);
#pragma unroll
        for (int j = 0; j < 3; ++j) {
            bf16x8 bf = *reinterpret_cast<const bf16x8*>(&Ws[(colbase + j * 16 + lr) * LDB + lg * 8]);
            acc[j] = __builtin_amdgcn_mfma_f32_16x16x32_bf16(af, bf, acc[j], 0, 0, 0);
        }
        __syncthreads();
    }

#pragma unroll
    for (int j = 0; j < 3; ++j) {
        int ncol = colbase + j * 16 + lr;
#pragma unroll
        for (int q = 0; q < 4; ++q) {
            int m = m0 + rowbase + lg * 4 + q;
            part[((size_t)ks * (B_ * L_) + m) * 96 + ncol] = acc[j][q];
        }
    }
}

// combiner: sum K-split partials, route to Bm / Cm / d1_bf
__global__ __launch_bounds__(256) void k_proj_sum(const float* __restrict__ part,
                                                  float* __restrict__ Bm,
                                                  float* __restrict__ Cm,
                                                  ushort* __restrict__ d1_bf) {
    int idx = blockIdx.x * 256 + threadIdx.x;   // 0 .. M*96-1
    int m = idx / 96, c = idx - m * 96;
    float v = 0.f;
#pragma unroll
    for (int ks = 0; ks < KS_; ++ks)
        v += part[((size_t)ks * (B_ * L_) + m) * 96 + c];
    if (c < 16)      Bm[(size_t)m * 16 + c] = v;
    else if (c < 32) Cm[(size_t)m * 16 + (c - 16)] = v;
    else             d1_bf[(size_t)m * 64 + (c - 32)] = f2bf(v);
}

// ---------------- depthwise causal conv1d + bias + silu (bf16 in/out) ----------------
__global__ __launch_bounds__(256) void k_conv_silu(const ushort* __restrict__ x,
                                                   const float* __restrict__ w,
                                                   const float* __restrict__ bias,
                                                   ushort* __restrict__ out_bf) {
    int idx = blockIdx.x * 256 + threadIdx.x;
    int e = idx & (E_ - 1);
    int l = (idx / E_) & (L_ - 1);
    float4 wv = *reinterpret_cast<const float4*>(&w[e * 4]);
    float acc = bias[e];
    acc = fmaf(wv.w, bf2f(x[idx]), acc);
    if (l >= 1) acc = fmaf(wv.z, bf2f(x[idx - E_]), acc);
    if (l >= 2) acc = fmaf(wv.y, bf2f(x[idx - 2 * E_]), acc);
    if (l >= 3) acc = fmaf(wv.x, bf2f(x[idx - 3 * E_]), acc);
    out_bf[idx] = f2bf(silu_f(acc));
}

// ================= segmented selective scan: 1 lane = 1 channel =================
__global__ __launch_bounds__(256, 8) void k_scan_p1(const ushort* __restrict__ xs,
                                                    const ushort* __restrict__ delta,
                                                    const float* __restrict__ Bm,
                                                    const float* __restrict__ A_log,
                                                    float* __restrict__ hbuf,
                                                    float* __restrict__ sdsum) {
    int t = threadIdx.x;
    int bid = blockIdx.x;
    int s = bid & (S_SEG - 1);
    int eblk = (bid >> 6) & 7;
    int b = bid >> 9;
    int e = eblk * 256 + t;

    float A2[16];
#pragma unroll
    for (int i = 0; i < 16; i += 4) {
        f32x4 al = *reinterpret_cast<const f32x4*>(&A_log[(size_t)e * 16 + i]);
#pragma unroll
        for (int j = 0; j < 4; ++j) A2[i + j] = -__expf(al[j]) * LOG2E_;
    }
    f32x4 h4[4] = {};
    float sdl = 0.f;

    const ushort* dp = delta + ((size_t)b * L_ + s * SEGLEN_) * E_ + e;
    const ushort* xp = xs    + ((size_t)b * L_ + s * SEGLEN_) * E_ + e;
    const float*  Bp = Bm + ((size_t)b * L_ + s * SEGLEN_) * 16;

    auto compute = [&](ushort du, ushort xu, int l) {
        float d = bf2f(du), xv = bf2f(xu);
        float dx = d * xv;
        sdl += d;
#pragma unroll
        for (int g = 0; g < 4; ++g) {
            f32x4 Bv = *reinterpret_cast<const f32x4*>(&Bp[l * 16 + g * 4]);
            f32x4 e4;
#pragma unroll
            for (int j = 0; j < 4; ++j) e4[j] = exp2f(d * A2[g * 4 + j]);
            h4[g] = e4 * h4[g] + dx * Bv;
        }
    };

    ushort duA = dp[0], xuA = xp[0];
    for (int l = 0; l < SEGLEN_; l += 2) {
        ushort duB = dp[(l + 1) * E_], xuB = xp[(l + 1) * E_];
        compute(duA, xuA, l);
        int ln = l + 2; if (ln > SEGLEN_ - 1) ln = SEGLEN_ - 1;
        duA = dp[ln * E_]; xuA = xp[ln * E_];
        compute(duB, xuB, l + 1);
    }

    size_t cidx = ((size_t)(b * S_SEG + s) * E_ + e) * 16;
#pragma unroll
    for (int g = 0; g < 4; ++g)
        *reinterpret_cast<f32x4*>(&hbuf[cidx + g * 4]) = h4[g];
    sdsum[(size_t)(b * S_SEG + s) * E_ + e] = sdl;
}

__global__ __launch_bounds__(256) void k_scan_p2(float* __restrict__ hbuf,
                                                 const float* __restrict__ sdsum,
                                                 const float* __restrict__ A_log) {
    int t = blockIdx.x * 256 + threadIdx.x;   // B*E*4 threads
    int q = t & 3;
    int e = (t >> 2) & (E_ - 1);
    int b = t >> 13;
    f32x4 A2;
    {
        f32x4 al = *reinterpret_cast<const f32x4*>(&A_log[(size_t)e * 16 + q * 4]);
#pragma unroll
        for (int i = 0; i < 4; ++i) A2[i] = -__expf(al[i]) * LOG2E_;
    }
    f32x4 acc = {0.f, 0.f, 0.f, 0.f};
    for (int s = 0; s < S_SEG; ++s) {
        size_t idx = ((size_t)(b * S_SEG + s) * E_ + e) * 16 + q * 4;
        f32x4 hl = *reinterpret_cast<const f32x4*>(&hbuf[idx]);
        float sd = sdsum[(size_t)(b * S_SEG + s) * E_ + e];
        *reinterpret_cast<f32x4*>(&hbuf[idx]) = acc;   // hbuf becomes h_in
        f32x4 p;
#pragma unroll
        for (int i = 0; i < 4; ++i) p[i] = exp2f(A2[i] * sd);
        acc = hl + p * acc;
    }
}

__global__ __launch_bounds__(256, 8) void k_scan_p3(const ushort* __restrict__ xs,
                                                    const ushort* __restrict__ delta,
                                                    const float* __restrict__ Bm,
                                                    const float* __restrict__ Cm,
                                                    const float* __restrict__ A_log,
                                                    const float* __restrict__ W_D,
                                                    const ushort* __restrict__ skip,
                                                    const float* __restrict__ hbuf,
                                                    ushort* __restrict__ yg) {
    int t = threadIdx.x;
    int bid = blockIdx.x;
    int s = bid & (S_SEG - 1);
    int eblk = (bid >> 6) & 7;
    int b = bid >> 9;
    int e = eblk * 256 + t;

    float A2[16];
#pragma unroll
    for (int i = 0; i < 16; i += 4) {
        f32x4 al = *reinterpret_cast<const f32x4*>(&A_log[(size_t)e * 16 + i]);
#pragma unroll
        for (int j = 0; j < 4; ++j) A2[i + j] = -__expf(al[j]) * LOG2E_;
    }
    size_t cidx = ((size_t)(b * S_SEG + s) * E_ + e) * 16;
    f32x4 h4[4];
#pragma unroll
    for (int g = 0; g < 4; ++g)
        h4[g] = *reinterpret_cast<const f32x4*>(&hbuf[cidx + g * 4]);
    float wd = W_D[e];

    const ushort* dp = delta + ((size_t)b * L_ + s * SEGLEN_) * E_ + e;
    const ushort* xp = xs    + ((size_t)b * L_ + s * SEGLEN_) * E_ + e;
    const ushort* sp = skip  + ((size_t)b * L_ + s * SEGLEN_) * E_ + e;
    const float*  Bp = Bm + ((size_t)b * L_ + s * SEGLEN_) * 16;
    const float*  Cp = Cm + ((size_t)b * L_ + s * SEGLEN_) * 16;
    ushort* yp = yg + ((size_t)b * L_ + s * SEGLEN_) * E_ + e;

    auto compute = [&](ushort du, ushort xu, ushort su, int l) {
        float d = bf2f(du), xv = bf2f(xu);
        float dx = d * xv;
        f32x4 yv = {0.f, 0.f, 0.f, 0.f};
#pragma unroll
        for (int g = 0; g < 4; ++g) {
            f32x4 Bv = *reinterpret_cast<const f32x4*>(&Bp[l * 16 + g * 4]);
            f32x4 Cv = *reinterpret_cast<const f32x4*>(&Cp[l * 16 + g * 4]);
            f32x4 e4;
#pragma unroll
            for (int j = 0; j < 4; ++j) e4[j] = exp2f(d * A2[g * 4 + j]);
            h4[g] = e4 * h4[g] + dx * Bv;
            yv = h4[g] * Cv + yv;
        }
        float y = (yv[0] + yv[1]) + (yv[2] + yv[3]);
        float gsk = silu_f(bf2f(su));
        yp[(size_t)l * E_] = f2bf((y + xv * wd) * gsk);
    };

    ushort duA = dp[0], xuA = xp[0], suA = sp[0];
    for (int l = 0; l < SEGLEN_; l += 2) {
        ushort duB = dp[(l + 1) * E_], xuB = xp[(l + 1) * E_], suB = sp[(l + 1) * E_];
        compute(duA, xuA, suA, l);
        int ln = l + 2; if (ln > SEGLEN_ - 1) ln = SEGLEN_ - 1;
        duA = dp[ln * E_]; xuA = xp[ln * E_]; suA = sp[ln * E_];
        compute(duB, xuB, suB, l + 1);
    }
}

extern "C" void kernel_launch(void* const* d_in, const int* in_sizes, int n_in,
                              void* d_out, int out_size, void* d_ws, size_t ws_size,
                              hipStream_t stream) {
    const float* resid  = (const float*)d_in[0];
    const float* norm_w = (const float*)d_in[1];
    const float* skip_w = (const float*)d_in[2];
    const float* in_w   = (const float*)d_in[3];
    const float* conv_w = (const float*)d_in[4];
    const float* conv_b = (const float*)d_in[5];
    const float* Wd1    = (const float*)d_in[6];
    const float* Wd2_w  = (const float*)d_in[7];
    const float* Wd2_b  = (const float*)d_in[8];
    const float* WB     = (const float*)d_in[9];
    const float* WC     = (const float*)d_in[10];
    const float* A_log  = (const float*)d_in[11];
    const float* W_D    = (const float*)d_in[12];
    const float* out_w  = (const float*)d_in[13];
    float* out = (float*)d_out;

    const int M = B_ * L_;                 // 8192
    char* p = (char*)d_ws;
    ushort* xn_bf    = (ushort*)p; p += (size_t)M * D_ * 2;        // 16.8 MB (proj partials alias)
    ushort* w2_bf    = (ushort*)p; p += (size_t)2 * E_ * D_ * 2;   // 8.4 MB
    ushort* outw_bf  = (ushort*)p; p += (size_t)D_ * E_ * 2;
    ushort* wbc_bf   = (ushort*)p; p += (size_t)96 * E_ * 2;
    ushort* wd2_bf   = (ushort*)p; p += (size_t)E_ * DD_ * 2;
    ushort* xin_bf   = (ushort*)p; p += (size_t)M * E_ * 2;
    ushort* xs_bf    = (ushort*)p; p += (size_t)M * E_ * 2;
    ushort* skip_bf  = (ushort*)p; p += (size_t)M * E_ * 2;
    ushort* delta_bf = (ushort*)p; p += (size_t)M * E_ * 2;
    ushort* yg_bf    = (ushort*)p; p += (size_t)M * E_ * 2;
    ushort* d1_bf    = (ushort*)p; p += (size_t)M * DD_ * 2;
    float*  Bm       = (float*)p;  p += (size_t)M * 16 * 4;
    float*  Cm       = (float*)p;  p += (size_t)M * 16 * 4;
    float*  hbuf     = (float*)p;  p += (size_t)B_ * S_SEG * E_ * 16 * 4;  // 33.5 MB
    float*  sdsum    = (float*)p;  p += (size_t)B_ * S_SEG * E_ * 4;       // 2.1 MB
    // proj K-split partials (12.6 MB) alias xn_bf (dead after fused GEMM)
    float*  proj_part = (float*)xn_bf;

    dim3 blk(256);

    // 0. all weight casts in one launch
    k_cast_all<<<dim3(6464), blk, 0, stream>>>(skip_w, in_w, out_w, WB, WC, Wd1, Wd2_w,
                                               w2_bf, outw_bf, wbc_bf, wd2_bf);
    // 1. RMSNorm -> bf16
    k_rmsnorm_bf<<<dim3(M), blk, 0, stream>>>(resid, norm_w, xn_bf);
    // 2+3. fused: [skip | xin] = xn @ [skip_w; in_w]^T  (N=4096, split bf16 epilogue)
    k_gemm_bf<3><<<dim3(2 * E_ / 128, M / 128), blk, 0, stream>>>(
        xn_bf, w2_bf, nullptr, nullptr, nullptr, skip_bf, xin_bf, M, 2 * E_, D_);
    // 4. xs = silu(conv(xin)+b) -> bf16
    k_conv_silu<<<dim3((M * E_) / 256), blk, 0, stream>>>(xin_bf, conv_w, conv_b, xs_bf);
    // 5+7. skinny projections, K-split-4 + combiner
    k_proj<<<dim3(M / 32, KS_), blk, 0, stream>>>(xs_bf, wbc_bf, proj_part);
    k_proj_sum<<<dim3((M * 96) / 256), blk, 0, stream>>>(proj_part, Bm, Cm, d1_bf);
    // 6. delta = softplus(d1 @ Wd2^T + b) -> bf16
    k_gemm_bf<1><<<dim3(E_ / 128, M / 128), blk, 0, stream>>>(
        d1_bf, wd2_bf, Wd2_b, nullptr, nullptr, delta_bf, nullptr, M, E_, DD_);
    // 8. segmented scan (S_SEG=64)
    k_scan_p1<<<dim3(B_ * S_SEG * (E_ / 256)), blk, 0, stream>>>(xs_bf, delta_bf, Bm, A_log, hbuf, sdsum);
    k_scan_p2<<<dim3((B_ * E_ * 4) / 256), blk, 0, stream>>>(hbuf, sdsum, A_log);
    k_scan_p3<<<dim3(B_ * S_SEG * (E_ / 256)), blk, 0, stream>>>(xs_bf, delta_bf, Bm, Cm, A_log,
                                                                  W_D, skip_bf, hbuf, yg_bf);
    // 9. out = resid + yg @ out_w^T
    k_gemm_bf<2><<<dim3(D_ / 128, M / 128), blk, 0, stream>>>(
        yg_bf, outw_bf, nullptr, resid, out, nullptr, nullptr, M, D_, E_);
}

// Round 11
// 544.887 us; speedup vs baseline: 1.2093x; 1.2093x over previous
//
#include <hip/hip_runtime.h>
#include <hip/hip_bf16.h>
#include <math.h>

#define B_ 4
#define L_ 2048
#define D_ 1024
#define E_ 2048
#define N_ 16
#define DD_ 64
#define DCONV_ 4

#define S_SEG 64
#define SEGLEN_ (L_ / S_SEG)   // 32

#define KS_ 4
#define KSUB_ (E_ / KS_)       // 512

typedef __attribute__((ext_vector_type(8))) short bf16x8;
typedef __attribute__((ext_vector_type(4))) float f32x4;

typedef __attribute__((address_space(1))) const void gvoid_t;
typedef __attribute__((address_space(3))) void lvoid_t;

static __device__ __forceinline__ float silu_f(float x) {
    return x / (1.f + __expf(-x));
}

// softplus via HW v_exp/v_log (1-ulp f32, far below bf16 rounding)
static __device__ __forceinline__ float softplus_f(float z) {
    return (z > 20.f) ? z : 0.69314718f * __log2f(1.f + exp2f(1.44269504f * z));
}

static __device__ __forceinline__ ushort f2bf(float f) {
    __hip_bfloat16 h = __float2bfloat16(f);
    return *reinterpret_cast<ushort*>(&h);
}

static __device__ __forceinline__ float bf2f(ushort u) {
    uint v = ((uint)u) << 16;
    return __uint_as_float(v);
}

#define LOG2E_ 1.4426950408889634f

// ---------------- RMSNorm: resid [B*L, D] -> xn (bf16) ----------------
__global__ __launch_bounds__(256) void k_rmsnorm_bf(const float* __restrict__ resid,
                                                    const float* __restrict__ nw,
                                                    ushort* __restrict__ out) {
    int row = blockIdx.x;
    const float* r = resid + (size_t)row * D_;
    int t = threadIdx.x;
    float4 v = *reinterpret_cast<const float4*>(&r[t * 4]);
    float ss = v.x * v.x + v.y * v.y + v.z * v.z + v.w * v.w;
#pragma unroll
    for (int o = 32; o >= 1; o >>= 1) ss += __shfl_xor(ss, o, 64);
    __shared__ float red[4];
    if ((t & 63) == 0) red[t >> 6] = ss;
    __syncthreads();
    float tot = red[0] + red[1] + red[2] + red[3];
    float rs = rsqrtf(tot * (1.f / (float)D_) + 1e-5f);
    float4 w4 = *reinterpret_cast<const float4*>(&nw[t * 4]);
    ushort4 o4;
    o4.x = f2bf(v.x * rs * w4.x);
    o4.y = f2bf(v.y * rs * w4.y);
    o4.z = f2bf(v.z * rs * w4.z);
    o4.w = f2bf(v.w * rs * w4.w);
    *reinterpret_cast<ushort4*>(&out[(size_t)row * D_ + t * 4]) = o4;
}

// ---------------- single fused f32->bf16 weight cast ----------------
__global__ __launch_bounds__(256) void k_cast_all(const float* __restrict__ skip_w,
                                                  const float* __restrict__ in_w,
                                                  const float* __restrict__ out_w,
                                                  const float* __restrict__ WB,
                                                  const float* __restrict__ WC,
                                                  const float* __restrict__ Wd1,
                                                  const float* __restrict__ Wd2,
                                                  ushort* __restrict__ w2,
                                                  ushort* __restrict__ outw,
                                                  ushort* __restrict__ wbc,
                                                  ushort* __restrict__ wd2) {
    int i = blockIdx.x * 256 + threadIdx.x;
    const float* src;
    ushort* dst;
    int off;
    if (i < 524288)       { src = skip_w; dst = w2;            off = i; }
    else if (i < 1048576) { src = in_w;   dst = w2 + 2097152;  off = i - 524288; }
    else if (i < 1572864) { src = out_w;  dst = outw;          off = i - 1048576; }
    else if (i < 1581056) { src = WB;     dst = wbc;           off = i - 1572864; }
    else if (i < 1589248) { src = WC;     dst = wbc + 32768;   off = i - 1581056; }
    else if (i < 1622016) { src = Wd1;    dst = wbc + 65536;   off = i - 1589248; }
    else                  { src = Wd2;    dst = wd2;           off = i - 1622016; }
    float4 v = *reinterpret_cast<const float4*>(&src[(size_t)off * 4]);
    ushort4 o;
    o.x = f2bf(v.x); o.y = f2bf(v.y); o.z = f2bf(v.z); o.w = f2bf(v.w);
    *reinterpret_cast<ushort4*>(&dst[(size_t)off * 4]) = o;
}

// ---------------- bf16 MFMA GEMM (global_load_lds staging, coalesced LDS epilogue) ----
// C = A[M,K] @ W[N,K]^T
// EPI 1: softplus(acc+bias[n]) -> bf16 Cbf (stride N)
// EPI 2: acc + addsrc -> f32 Cf (stride N)
// EPI 3: split at ncol 2048: bf16 Cbf (skip) / bf16 Cbf2 (xin), both stride 2048
template <int EPI>
__global__ __launch_bounds__(256) void k_gemm_bf(const ushort* __restrict__ A,
                                                 const ushort* __restrict__ W,
                                                 const float* __restrict__ bias,
                                                 const float* __restrict__ addsrc,
                                                 float* __restrict__ Cf,
                                                 ushort* __restrict__ Cbf,
                                                 ushort* __restrict__ Cbf2,
                                                 int M, int N, int K) {
    constexpr int BM = 128, BN = 128, BK = 32;
    constexpr int EPAD = 68;   // 272B row stride: epilogue phases = 2 lanes/bank (free)
    union SM {
        ushort stage[2 * BM * BK];     // As | Ws  (16 KB)
        float  epi[4][16][EPAD];       // per-wave epilogue scratch (17.4 KB)
    };
    __shared__ __align__(16) SM sm;
    ushort* As = sm.stage;
    ushort* Ws = sm.stage + BM * BK;

    int t = threadIdx.x;
    int m0 = blockIdx.y * BM, n0 = blockIdx.x * BN;
    int wave = t >> 6, lane = t & 63;
    int wr = wave >> 1, wc = wave & 1;
    int lr = lane & 15, lg = lane >> 4;
    int srow = lane >> 2;
    int scol = (lane & 3) * 8;

    f32x4 acc[4][4] = {};

    for (int k0 = 0; k0 < K; k0 += BK) {
#pragma unroll
        for (int p = 0; p < 2; ++p) {
            int seg = wave * 2 + p;
            int row = seg * 16 + srow;
            __builtin_amdgcn_global_load_lds(
                (gvoid_t*)(A + (size_t)(m0 + row) * K + k0 + scol),
                (lvoid_t*)(As + seg * 512), 16, 0, 0);
            __builtin_amdgcn_global_load_lds(
                (gvoid_t*)(W + (size_t)(n0 + row) * K + k0 + scol),
                (lvoid_t*)(Ws + seg * 512), 16, 0, 0);
        }
        __syncthreads();
        bf16x8 af[4], bfr[4];
#pragma unroll
        for (int i = 0; i < 4; ++i) {
            af[i]  = *reinterpret_cast<const bf16x8*>(&As[(wr * 64 + i * 16 + lr) * BK + lg * 8]);
            bfr[i] = *reinterpret_cast<const bf16x8*>(&Ws[(wc * 64 + i * 16 + lr) * BK + lg * 8]);
        }
#pragma unroll
        for (int i = 0; i < 4; ++i)
#pragma unroll
            for (int j = 0; j < 4; ++j)
                acc[i][j] = __builtin_amdgcn_mfma_f32_16x16x32_bf16(af[i], bfr[j], acc[i][j], 0, 0, 0);
        __syncthreads();
    }

    // ---- coalesced epilogue: per-wave 16x64 subtile through LDS ----
    int er = lane >> 2;            // 0..15 row within subtile
    int ec = (lane & 3) * 16;      // col chunk base (16 elems)
#pragma unroll
    for (int i = 0; i < 4; ++i) {
#pragma unroll
        for (int j = 0; j < 4; ++j)
#pragma unroll
            for (int q = 0; q < 4; ++q)
                sm.epi[wave][lg * 4 + q][j * 16 + lr] = acc[i][j][q];
        float vals[16];
#pragma unroll
        for (int v4 = 0; v4 < 4; ++v4) {
            f32x4 tmp = *reinterpret_cast<const f32x4*>(&sm.epi[wave][er][ec + v4 * 4]);
            vals[v4 * 4 + 0] = tmp[0]; vals[v4 * 4 + 1] = tmp[1];
            vals[v4 * 4 + 2] = tmp[2]; vals[v4 * 4 + 3] = tmp[3];
        }
        int grow = m0 + wr * 64 + i * 16 + er;
        int gcol = n0 + wc * 64 + ec;

        if (EPI == 1) {
            ushort u[16];
#pragma unroll
            for (int k = 0; k < 16; ++k)
                u[k] = f2bf(softplus_f(vals[k] + bias[gcol + k]));
            *reinterpret_cast<uint4*>(&Cbf[(size_t)grow * N + gcol]) = *reinterpret_cast<uint4*>(&u[0]);
            *reinterpret_cast<uint4*>(&Cbf[(size_t)grow * N + gcol + 8]) = *reinterpret_cast<uint4*>(&u[8]);
        } else if (EPI == 2) {
#pragma unroll
            for (int v4 = 0; v4 < 4; ++v4) {
                f32x4 r4 = *reinterpret_cast<const f32x4*>(&addsrc[(size_t)grow * N + gcol + v4 * 4]);
                f32x4 o4;
#pragma unroll
                for (int k = 0; k < 4; ++k) o4[k] = vals[v4 * 4 + k] + r4[k];
                *reinterpret_cast<f32x4*>(&Cf[(size_t)grow * N + gcol + v4 * 4]) = o4;
            }
        } else {  // EPI == 3
            ushort u[16];
#pragma unroll
            for (int k = 0; k < 16; ++k) u[k] = f2bf(vals[k]);
            if (gcol < 2048) {
                *reinterpret_cast<uint4*>(&Cbf[(size_t)grow * 2048 + gcol]) = *reinterpret_cast<uint4*>(&u[0]);
                *reinterpret_cast<uint4*>(&Cbf[(size_t)grow * 2048 + gcol + 8]) = *reinterpret_cast<uint4*>(&u[8]);
            } else {
                int c2 = gcol - 2048;
                *reinterpret_cast<uint4*>(&Cbf2[(size_t)grow * 2048 + c2]) = *reinterpret_cast<uint4*>(&u[0]);
                *reinterpret_cast<uint4*>(&Cbf2[(size_t)grow * 2048 + c2 + 8]) = *reinterpret_cast<uint4*>(&u[8]);
            }
        }
    }
}

// ---------------- skinny projections, K-split: part[ks][M][96] = xs_bf @ wbc^T ----------------
__global__ __launch_bounds__(256) void k_proj(const ushort* __restrict__ A,
                                              const ushort* __restrict__ Wc,
                                              float* __restrict__ part) {
    constexpr int BK = 32, LDB = 40;
    __shared__ __align__(16) ushort As[32 * LDB];
    __shared__ __align__(16) ushort Ws[96 * LDB];
    int t = threadIdx.x;
    int m0 = blockIdx.x * 32;
    int ks = blockIdx.y;
    int wave = t >> 6, lane = t & 63;
    int rowbase = (wave >> 1) * 16;
    int colbase = (wave & 1) * 48;
    int lr = lane & 15, lg = lane >> 4;

    f32x4 acc[3] = {};

    for (int k0 = ks * KSUB_; k0 < (ks + 1) * KSUB_; k0 += BK) {
        if (t < 128) {
            int row = t >> 2;
            int cg = (t & 3) * 8;
            *reinterpret_cast<uint4*>(&As[row * LDB + cg]) =
                *reinterpret_cast<const uint4*>(&A[(size_t)(m0 + row) * E_ + k0 + cg]);
        }
        {
            int row = t >> 2, cg = (t & 3) * 8;
            *reinterpret_cast<uint4*>(&Ws[row * LDB + cg]) =
                *reinterpret_cast<const uint4*>(&Wc[(size_t)row * E_ + k0 + cg]);
            if (t < 128) {
                int f2 = t + 256;
                int row2 = f2 >> 2, cg2 = (f2 & 3) * 8;
                *reinterpret_cast<uint4*>(&Ws[row2 * LDB + cg2]) =
                    *reinterpret_cast<const uint4*>(&Wc[(size_t)row2 * E_ + k0 + cg2]);
            }
        }
        __syncthreads();
        bf16x8 af = *reinterpret_cast<const bf16x8*>(&As[(rowbase + lr) * LDB + lg * 8]);
#pragma unroll
        for (int j = 0; j < 3; ++j) {
            bf16x8 bf = *reinterpret_cast<const bf16x8*>(&Ws[(colbase + j * 16 + lr) * LDB + lg * 8]);
            acc[j] = __builtin_amdgcn_mfma_f32_16x16x32_bf16(af, bf, acc[j], 0, 0, 0);
        }
        __syncthreads();
    }

#pragma unroll
    for (int j = 0; j < 3; ++j) {
        int ncol = colbase + j * 16 + lr;
#pragma unroll
        for (int q = 0; q < 4; ++q) {
            int m = m0 + rowbase + lg * 4 + q;
            part[((size_t)ks * (B_ * L_) + m) * 96 + ncol] = acc[j][q];
        }
    }
}

// combiner: sum K-split partials, route to Bm / Cm / d1_bf
__global__ __launch_bounds__(256) void k_proj_sum(const float* __restrict__ part,
                                                  float* __restrict__ Bm,
                                                  float* __restrict__ Cm,
                                                  ushort* __restrict__ d1_bf) {
    int idx = blockIdx.x * 256 + threadIdx.x;   // 0 .. M*96-1
    int m = idx / 96, c = idx - m * 96;
    float v = 0.f;
#pragma unroll
    for (int ks = 0; ks < KS_; ++ks)
        v += part[((size_t)ks * (B_ * L_) + m) * 96 + c];
    if (c < 16)      Bm[(size_t)m * 16 + c] = v;
    else if (c < 32) Cm[(size_t)m * 16 + (c - 16)] = v;
    else             d1_bf[(size_t)m * 64 + (c - 32)] = f2bf(v);
}

// ---------------- depthwise causal conv1d + bias + silu (bf16 in/out) ----------------
__global__ __launch_bounds__(256) void k_conv_silu(const ushort* __restrict__ x,
                                                   const float* __restrict__ w,
                                                   const float* __restrict__ bias,
                                                   ushort* __restrict__ out_bf) {
    int idx = blockIdx.x * 256 + threadIdx.x;
    int e = idx & (E_ - 1);
    int l = (idx / E_) & (L_ - 1);
    float4 wv = *reinterpret_cast<const float4*>(&w[e * 4]);
    float acc = bias[e];
    acc = fmaf(wv.w, bf2f(x[idx]), acc);
    if (l >= 1) acc = fmaf(wv.z, bf2f(x[idx - E_]), acc);
    if (l >= 2) acc = fmaf(wv.y, bf2f(x[idx - 2 * E_]), acc);
    if (l >= 3) acc = fmaf(wv.x, bf2f(x[idx - 3 * E_]), acc);
    out_bf[idx] = f2bf(silu_f(acc));
}

// ================= segmented selective scan: 1 lane = 1 channel =================
__global__ __launch_bounds__(256, 8) void k_scan_p1(const ushort* __restrict__ xs,
                                                    const ushort* __restrict__ delta,
                                                    const float* __restrict__ Bm,
                                                    const float* __restrict__ A_log,
                                                    float* __restrict__ hbuf,
                                                    float* __restrict__ sdsum) {
    int t = threadIdx.x;
    int bid = blockIdx.x;
    int s = bid & (S_SEG - 1);
    int eblk = (bid >> 6) & 7;
    int b = bid >> 9;
    int e = eblk * 256 + t;

    float A2[16];
#pragma unroll
    for (int i = 0; i < 16; i += 4) {
        f32x4 al = *reinterpret_cast<const f32x4*>(&A_log[(size_t)e * 16 + i]);
#pragma unroll
        for (int j = 0; j < 4; ++j) A2[i + j] = -__expf(al[j]) * LOG2E_;
    }
    f32x4 h4[4] = {};
    float sdl = 0.f;

    const ushort* dp = delta + ((size_t)b * L_ + s * SEGLEN_) * E_ + e;
    const ushort* xp = xs    + ((size_t)b * L_ + s * SEGLEN_) * E_ + e;
    const float*  Bp = Bm + ((size_t)b * L_ + s * SEGLEN_) * 16;

    auto compute = [&](ushort du, ushort xu, int l) {
        float d = bf2f(du), xv = bf2f(xu);
        float dx = d * xv;
        sdl += d;
#pragma unroll
        for (int g = 0; g < 4; ++g) {
            f32x4 Bv = *reinterpret_cast<const f32x4*>(&Bp[l * 16 + g * 4]);
            f32x4 e4;
#pragma unroll
            for (int j = 0; j < 4; ++j) e4[j] = exp2f(d * A2[g * 4 + j]);
            h4[g] = e4 * h4[g] + dx * Bv;
        }
    };

    ushort duA = dp[0], xuA = xp[0];
    for (int l = 0; l < SEGLEN_; l += 2) {
        ushort duB = dp[(l + 1) * E_], xuB = xp[(l + 1) * E_];
        compute(duA, xuA, l);
        int ln = l + 2; if (ln > SEGLEN_ - 1) ln = SEGLEN_ - 1;
        duA = dp[ln * E_]; xuA = xp[ln * E_];
        compute(duB, xuB, l + 1);
    }

    size_t cidx = ((size_t)(b * S_SEG + s) * E_ + e) * 16;
#pragma unroll
    for (int g = 0; g < 4; ++g)
        *reinterpret_cast<f32x4*>(&hbuf[cidx + g * 4]) = h4[g];
    sdsum[(size_t)(b * S_SEG + s) * E_ + e] = sdl;
}

__global__ __launch_bounds__(256) void k_scan_p2(float* __restrict__ hbuf,
                                                 const float* __restrict__ sdsum,
                                                 const float* __restrict__ A_log) {
    int t = blockIdx.x * 256 + threadIdx.x;   // B*E*4 threads
    int q = t & 3;
    int e = (t >> 2) & (E_ - 1);
    int b = t >> 13;
    f32x4 A2;
    {
        f32x4 al = *reinterpret_cast<const f32x4*>(&A_log[(size_t)e * 16 + q * 4]);
#pragma unroll
        for (int i = 0; i < 4; ++i) A2[i] = -__expf(al[i]) * LOG2E_;
    }
    f32x4 acc = {0.f, 0.f, 0.f, 0.f};
    for (int s = 0; s < S_SEG; ++s) {
        size_t idx = ((size_t)(b * S_SEG + s) * E_ + e) * 16 + q * 4;
        f32x4 hl = *reinterpret_cast<const f32x4*>(&hbuf[idx]);
        float sd = sdsum[(size_t)(b * S_SEG + s) * E_ + e];
        *reinterpret_cast<f32x4*>(&hbuf[idx]) = acc;   // hbuf becomes h_in
        f32x4 p;
#pragma unroll
        for (int i = 0; i < 4; ++i) p[i] = exp2f(A2[i] * sd);
        acc = hl + p * acc;
    }
}

__global__ __launch_bounds__(256, 8) void k_scan_p3(const ushort* __restrict__ xs,
                                                    const ushort* __restrict__ delta,
                                                    const float* __restrict__ Bm,
                                                    const float* __restrict__ Cm,
                                                    const float* __restrict__ A_log,
                                                    const float* __restrict__ W_D,
                                                    const ushort* __restrict__ skip,
                                                    const float* __restrict__ hbuf,
                                                    ushort* __restrict__ yg) {
    int t = threadIdx.x;
    int bid = blockIdx.x;
    int s = bid & (S_SEG - 1);
    int eblk = (bid >> 6) & 7;
    int b = bid >> 9;
    int e = eblk * 256 + t;

    float A2[16];
#pragma unroll
    for (int i = 0; i < 16; i += 4) {
        f32x4 al = *reinterpret_cast<const f32x4*>(&A_log[(size_t)e * 16 + i]);
#pragma unroll
        for (int j = 0; j < 4; ++j) A2[i + j] = -__expf(al[j]) * LOG2E_;
    }
    size_t cidx = ((size_t)(b * S_SEG + s) * E_ + e) * 16;
    f32x4 h4[4];
#pragma unroll
    for (int g = 0; g < 4; ++g)
        h4[g] = *reinterpret_cast<const f32x4*>(&hbuf[cidx + g * 4]);
    float wd = W_D[e];

    const ushort* dp = delta + ((size_t)b * L_ + s * SEGLEN_) * E_ + e;
    const ushort* xp = xs    + ((size_t)b * L_ + s * SEGLEN_) * E_ + e;
    const ushort* sp = skip  + ((size_t)b * L_ + s * SEGLEN_) * E_ + e;
    const float*  Bp = Bm + ((size_t)b * L_ + s * SEGLEN_) * 16;
    const float*  Cp = Cm + ((size_t)b * L_ + s * SEGLEN_) * 16;
    ushort* yp = yg + ((size_t)b * L_ + s * SEGLEN_) * E_ + e;

    auto compute = [&](ushort du, ushort xu, ushort su, int l) {
        float d = bf2f(du), xv = bf2f(xu);
        float dx = d * xv;
        f32x4 yv = {0.f, 0.f, 0.f, 0.f};
#pragma unroll
        for (int g = 0; g < 4; ++g) {
            f32x4 Bv = *reinterpret_cast<const f32x4*>(&Bp[l * 16 + g * 4]);
            f32x4 Cv = *reinterpret_cast<const f32x4*>(&Cp[l * 16 + g * 4]);
            f32x4 e4;
#pragma unroll
            for (int j = 0; j < 4; ++j) e4[j] = exp2f(d * A2[g * 4 + j]);
            h4[g] = e4 * h4[g] + dx * Bv;
            yv = h4[g] * Cv + yv;
        }
        float y = (yv[0] + yv[1]) + (yv[2] + yv[3]);
        float gsk = silu_f(bf2f(su));
        yp[(size_t)l * E_] = f2bf((y + xv * wd) * gsk);
    };

    ushort duA = dp[0], xuA = xp[0], suA = sp[0];
    for (int l = 0; l < SEGLEN_; l += 2) {
        ushort duB = dp[(l + 1) * E_], xuB = xp[(l + 1) * E_], suB = sp[(l + 1) * E_];
        compute(duA, xuA, suA, l);
        int ln = l + 2; if (ln > SEGLEN_ - 1) ln = SEGLEN_ - 1;
        duA = dp[ln * E_]; xuA = xp[ln * E_]; suA = sp[ln * E_];
        compute(duB, xuB, suB, l + 1);
    }
}

extern "C" void kernel_launch(void* const* d_in, const int* in_sizes, int n_in,
                              void* d_out, int out_size, void* d_ws, size_t ws_size,
                              hipStream_t stream) {
    const float* resid  = (const float*)d_in[0];
    const float* norm_w = (const float*)d_in[1];
    const float* skip_w = (const float*)d_in[2];
    const float* in_w   = (const float*)d_in[3];
    const float* conv_w = (const float*)d_in[4];
    const float* conv_b = (const float*)d_in[5];
    const float* Wd1    = (const float*)d_in[6];
    const float* Wd2_w  = (const float*)d_in[7];
    const float* Wd2_b  = (const float*)d_in[8];
    const float* WB     = (const float*)d_in[9];
    const float* WC     = (const float*)d_in[10];
    const float* A_log  = (const float*)d_in[11];
    const float* W_D    = (const float*)d_in[12];
    const float* out_w  = (const float*)d_in[13];
    float* out = (float*)d_out;

    const int M = B_ * L_;                 // 8192
    char* p = (char*)d_ws;
    ushort* xn_bf    = (ushort*)p; p += (size_t)M * D_ * 2;        // 16.8 MB (proj partials alias)
    ushort* w2_bf    = (ushort*)p; p += (size_t)2 * E_ * D_ * 2;   // 8.4 MB
    ushort* outw_bf  = (ushort*)p; p += (size_t)D_ * E_ * 2;
    ushort* wbc_bf   = (ushort*)p; p += (size_t)96 * E_ * 2;
    ushort* wd2_bf   = (ushort*)p; p += (size_t)E_ * DD_ * 2;
    ushort* xin_bf   = (ushort*)p; p += (size_t)M * E_ * 2;
    ushort* xs_bf    = (ushort*)p; p += (size_t)M * E_ * 2;
    ushort* skip_bf  = (ushort*)p; p += (size_t)M * E_ * 2;
    ushort* delta_bf = (ushort*)p; p += (size_t)M * E_ * 2;
    ushort* yg_bf    = (ushort*)p; p += (size_t)M * E_ * 2;
    ushort* d1_bf    = (ushort*)p; p += (size_t)M * DD_ * 2;
    float*  Bm       = (float*)p;  p += (size_t)M * 16 * 4;
    float*  Cm       = (float*)p;  p += (size_t)M * 16 * 4;
    float*  hbuf     = (float*)p;  p += (size_t)B_ * S_SEG * E_ * 16 * 4;  // 33.5 MB
    float*  sdsum    = (float*)p;  p += (size_t)B_ * S_SEG * E_ * 4;       // 2.1 MB
    // proj K-split partials (12.6 MB) alias xn_bf (dead after fused GEMM)
    float*  proj_part = (float*)xn_bf;

    dim3 blk(256);

    // 0. all weight casts in one launch
    k_cast_all<<<dim3(6464), blk, 0, stream>>>(skip_w, in_w, out_w, WB, WC, Wd1, Wd2_w,
                                               w2_bf, outw_bf, wbc_bf, wd2_bf);
    // 1. RMSNorm -> bf16
    k_rmsnorm_bf<<<dim3(M), blk, 0, stream>>>(resid, norm_w, xn_bf);
    // 2+3. fused: [skip | xin] = xn @ [skip_w; in_w]^T  (N=4096, split bf16 epilogue)
    k_gemm_bf<3><<<dim3(2 * E_ / 128, M / 128), blk, 0, stream>>>(
        xn_bf, w2_bf, nullptr, nullptr, nullptr, skip_bf, xin_bf, M, 2 * E_, D_);
    // 4. xs = silu(conv(xin)+b) -> bf16
    k_conv_silu<<<dim3((M * E_) / 256), blk, 0, stream>>>(xin_bf, conv_w, conv_b, xs_bf);
    // 5+7. skinny projections, K-split-4 + combiner
    k_proj<<<dim3(M / 32, KS_), blk, 0, stream>>>(xs_bf, wbc_bf, proj_part);
    k_proj_sum<<<dim3((M * 96) / 256), blk, 0, stream>>>(proj_part, Bm, Cm, d1_bf);
    // 6. delta = softplus(d1 @ Wd2^T + b) -> bf16  (HW-exp2/log2 softplus)
    k_gemm_bf<1><<<dim3(E_ / 128, M / 128), blk, 0, stream>>>(
        d1_bf, wd2_bf, Wd2_b, nullptr, nullptr, delta_bf, nullptr, M, E_, DD_);
    // 8. segmented scan (S_SEG=64)
    k_scan_p1<<<dim3(B_ * S_SEG * (E_ / 256)), blk, 0, stream>>>(xs_bf, delta_bf, Bm, A_log, hbuf, sdsum);
    k_scan_p2<<<dim3((B_ * E_ * 4) / 256), blk, 0, stream>>>(hbuf, sdsum, A_log);
    k_scan_p3<<<dim3(B_ * S_SEG * (E_ / 256)), blk, 0, stream>>>(xs_bf, delta_bf, Bm, Cm, A_log,
                                                                  W_D, skip_bf, hbuf, yg_bf);
    // 9. out = resid + yg @ out_w^T
    k_gemm_bf<2><<<dim3(D_ / 128, M / 128), blk, 0, stream>>>(
        yg_bf, outw_bf, nullptr, resid, out, nullptr, nullptr, M, D_, E_);
}